// Round 2
// baseline (2710.567 us; speedup 1.0000x reference)
//
#include <hip/hip_runtime.h>
#include <math.h>

#define B_   16
#define T_   2048
#define S_   2048
#define H_   1024
#define H2_  2048

typedef _Float16 h16;
typedef h16  half8 __attribute__((ext_vector_type(8)));
typedef h16  half4 __attribute__((ext_vector_type(4)));
typedef float f32x4 __attribute__((ext_vector_type(4)));

#define MFMA16 __builtin_amdgcn_mfma_f32_16x16x32_f16

__device__ __forceinline__ h16 hi_of(float x) { return (h16)x; }
__device__ __forceinline__ h16 lo_of(float x, h16 h) { return (h16)(x - (float)h); }

// split a float4 into hi/lo half4s
__device__ __forceinline__ void split4(const float4 v, half4& hi, half4& lo) {
    h16 h0 = (h16)v.x, h1 = (h16)v.y, h2 = (h16)v.z, h3 = (h16)v.w;
    hi[0] = h0; hi[1] = h1; hi[2] = h2; hi[3] = h3;
    lo[0] = (h16)(v.x - (float)h0);
    lo[1] = (h16)(v.y - (float)h1);
    lo[2] = (h16)(v.z - (float)h2);
    lo[3] = (h16)(v.w - (float)h3);
}

__device__ __forceinline__ half4 cvt4(const float4 v) {
    half4 r;
    r[0] = (h16)v.x; r[1] = (h16)v.y; r[2] = (h16)v.z; r[3] = (h16)v.w;
    return r;
}

// ---------------- K1: logits = dec @ enc^T  (fp16 hi/lo split, 3-pass) -------
__global__ __launch_bounds__(256)
void qk_kernel(const float* __restrict__ dec, const float* __restrict__ enc,
               float* __restrict__ logits) {
    __shared__ __align__(16) h16 Ah[128*40], Al[128*40], Bh[128*40], Bl[128*40];
    const int tid  = threadIdx.x;
    const int sb = blockIdx.x, tb = blockIdx.y, b = blockIdx.z;
    const int wave = tid >> 6, lane = tid & 63;
    const int wm = wave & 1, wn = wave >> 1;
    const int ml = lane & 15, quad = lane >> 4;

    const float* Abase = dec + ((size_t)b * T_ + (size_t)tb * 128) * (size_t)H_;
    const float* Bbase = enc + ((size_t)b * S_ + (size_t)sb * 128) * (size_t)H_;

    f32x4 acc[4][4];
#pragma unroll
    for (int i = 0; i < 4; i++)
#pragma unroll
        for (int j = 0; j < 4; j++) acc[i][j] = (f32x4){0.f, 0.f, 0.f, 0.f};

    for (int k0 = 0; k0 < H_; k0 += 32) {
#pragma unroll
        for (int f = tid; f < 1024; f += 256) {
            const int row = f >> 3, c4 = (f & 7) << 2;
            const float4 va = *(const float4*)(Abase + (size_t)row * H_ + k0 + c4);
            const float4 vb = *(const float4*)(Bbase + (size_t)row * H_ + k0 + c4);
            half4 ah, al, bh, bl;
            split4(va, ah, al);
            split4(vb, bh, bl);
            const int base = row * 40 + c4;
            *(half4*)&Ah[base] = ah; *(half4*)&Al[base] = al;
            *(half4*)&Bh[base] = bh; *(half4*)&Bl[base] = bl;
        }
        __syncthreads();
        half8 a_h[4], a_l[4], b_h[4], b_l[4];
#pragma unroll
        for (int i = 0; i < 4; i++) {
            const int ra = (wm * 64 + i * 16 + ml) * 40 + quad * 8;
            a_h[i] = *(const half8*)&Ah[ra];
            a_l[i] = *(const half8*)&Al[ra];
            const int rb = (wn * 64 + i * 16 + ml) * 40 + quad * 8;
            b_h[i] = *(const half8*)&Bh[rb];
            b_l[i] = *(const half8*)&Bl[rb];
        }
#pragma unroll
        for (int i = 0; i < 4; i++)
#pragma unroll
            for (int j = 0; j < 4; j++) {
                acc[i][j] = MFMA16(a_h[i], b_h[j], acc[i][j], 0, 0, 0);
                acc[i][j] = MFMA16(a_h[i], b_l[j], acc[i][j], 0, 0, 0);
                acc[i][j] = MFMA16(a_l[i], b_h[j], acc[i][j], 0, 0, 0);
            }
        __syncthreads();
    }
    float* Cbase = logits + ((size_t)b * T_ + (size_t)tb * 128) * (size_t)S_ + (size_t)sb * 128;
#pragma unroll
    for (int i = 0; i < 4; i++)
#pragma unroll
        for (int j = 0; j < 4; j++)
#pragma unroll
            for (int r = 0; r < 4; r++) {
                const int rr = wm * 64 + i * 16 + quad * 4 + r;
                const int cc = wn * 64 + j * 16 + ml;
                Cbase[(size_t)rr * S_ + cc] = acc[i][j][r];
            }
}

// ---------------- K2: row softmax over s (in place) --------------------------
__global__ __launch_bounds__(256)
void softmax_kernel(float* __restrict__ attn) {
    float* p = attn + (size_t)blockIdx.x * S_;
    const int tid = threadIdx.x;
    float v[8];
    float m = -1e30f;
#pragma unroll
    for (int i = 0; i < 8; i++) { v[i] = p[tid + i * 256]; m = fmaxf(m, v[i]); }
#pragma unroll
    for (int off = 32; off > 0; off >>= 1) m = fmaxf(m, __shfl_xor(m, off));
    __shared__ float sm[4];
    __shared__ float ss[4];
    if ((tid & 63) == 0) sm[tid >> 6] = m;
    __syncthreads();
    m = fmaxf(fmaxf(sm[0], sm[1]), fmaxf(sm[2], sm[3]));
    float s = 0.f;
#pragma unroll
    for (int i = 0; i < 8; i++) { v[i] = __expf(v[i] - m); s += v[i]; }
#pragma unroll
    for (int off = 32; off > 0; off >>= 1) s += __shfl_xor(s, off);
    if ((tid & 63) == 0) ss[tid >> 6] = s;
    __syncthreads();
    s = ss[0] + ss[1] + ss[2] + ss[3];
    const float inv = 1.0f / s;
#pragma unroll
    for (int i = 0; i < 8; i++) p[tid + i * 256] = v[i] * inv;
}

// ---------------- K3: ctx = attn @ enc  (f16, B transposed on stage) ---------
__global__ __launch_bounds__(256)
void av_kernel(const float* __restrict__ attn, const float* __restrict__ enc,
               h16* __restrict__ ctx) {
    __shared__ __align__(16) h16 Ah[128*40], Bt[128*40];
    const int tid = threadIdx.x;
    const int hb = blockIdx.x, tb = blockIdx.y, b = blockIdx.z;
    const int wave = tid >> 6, lane = tid & 63;
    const int wm = wave & 1, wn = wave >> 1;
    const int ml = lane & 15, quad = lane >> 4;

    const float* Abase = attn + ((size_t)b * T_ + (size_t)tb * 128) * (size_t)S_;
    const float* Bbase = enc + (size_t)b * S_ * H_ + (size_t)hb * 128;

    f32x4 acc[4][4];
#pragma unroll
    for (int i = 0; i < 4; i++)
#pragma unroll
        for (int j = 0; j < 4; j++) acc[i][j] = (f32x4){0.f, 0.f, 0.f, 0.f};

    for (int k0 = 0; k0 < S_; k0 += 32) {
#pragma unroll
        for (int f = tid; f < 1024; f += 256) {
            const int row = f >> 3, c4 = (f & 7) << 2;
            const float4 va = *(const float4*)(Abase + (size_t)row * S_ + k0 + c4);
            *(half4*)&Ah[row * 40 + c4] = cvt4(va);
        }
#pragma unroll
        for (int f = tid; f < 1024; f += 256) {
            const int kr = f >> 5, c4 = (f & 31) << 2;
            const float4 vb = *(const float4*)(Bbase + (size_t)(k0 + kr) * H_ + c4);
            Bt[(c4 + 0) * 40 + kr] = (h16)vb.x;
            Bt[(c4 + 1) * 40 + kr] = (h16)vb.y;
            Bt[(c4 + 2) * 40 + kr] = (h16)vb.z;
            Bt[(c4 + 3) * 40 + kr] = (h16)vb.w;
        }
        __syncthreads();
        half8 a_f[4], b_f[4];
#pragma unroll
        for (int i = 0; i < 4; i++) {
            a_f[i] = *(const half8*)&Ah[(wm * 64 + i * 16 + ml) * 40 + quad * 8];
            b_f[i] = *(const half8*)&Bt[(wn * 64 + i * 16 + ml) * 40 + quad * 8];
        }
#pragma unroll
        for (int i = 0; i < 4; i++)
#pragma unroll
            for (int j = 0; j < 4; j++)
                acc[i][j] = MFMA16(a_f[i], b_f[j], acc[i][j], 0, 0, 0);
        __syncthreads();
    }
    h16* Cbase = ctx + ((size_t)b * T_ + (size_t)tb * 128) * (size_t)H_ + (size_t)hb * 128;
#pragma unroll
    for (int i = 0; i < 4; i++)
#pragma unroll
        for (int j = 0; j < 4; j++)
#pragma unroll
            for (int r = 0; r < 4; r++) {
                const int rr = wm * 64 + i * 16 + quad * 4 + r;
                const int cc = wn * 64 + j * 16 + ml;
                Cbase[(size_t)rr * H_ + cc] = (h16)acc[i][j][r];
            }
}

// ---------------- K4: out = tanh([ctx, dec] @ W^T + bias) --------------------
__global__ __launch_bounds__(256)
void out_kernel(const h16* __restrict__ ctx, const float* __restrict__ dec,
                const float* __restrict__ W, const float* __restrict__ bias,
                float* __restrict__ out) {
    __shared__ __align__(16) h16 Ah[128*40], Bh[128*40];
    const int tid = threadIdx.x;
    const int hb = blockIdx.x, rb = blockIdx.y;   // rb: 0..255 row blocks over B*T
    const int wave = tid >> 6, lane = tid & 63;
    const int wm = wave & 1, wn = wave >> 1;
    const int ml = lane & 15, quad = lane >> 4;

    const h16*  A1 = ctx + (size_t)rb * 128 * H_;   // [128][1024] f16
    const float* A2 = dec + (size_t)rb * 128 * H_;  // [128][1024] f32
    const float* Bbase = W + (size_t)hb * 128 * H2_;

    f32x4 acc[4][4];
#pragma unroll
    for (int i = 0; i < 4; i++)
#pragma unroll
        for (int j = 0; j < 4; j++) acc[i][j] = (f32x4){0.f, 0.f, 0.f, 0.f};

    for (int k0 = 0; k0 < H2_; k0 += 32) {
        if (k0 < H_) {
#pragma unroll
            for (int f = tid; f < 512; f += 256) {
                const int row = f >> 2, c8 = (f & 3) << 3;
                const half8 v = *(const half8*)(A1 + (size_t)row * H_ + k0 + c8);
                *(half8*)&Ah[row * 40 + c8] = v;
            }
        } else {
#pragma unroll
            for (int f = tid; f < 1024; f += 256) {
                const int row = f >> 3, c4 = (f & 7) << 2;
                const float4 va = *(const float4*)(A2 + (size_t)row * H_ + (k0 - H_) + c4);
                *(half4*)&Ah[row * 40 + c4] = cvt4(va);
            }
        }
#pragma unroll
        for (int f = tid; f < 1024; f += 256) {
            const int row = f >> 3, c4 = (f & 7) << 2;
            const float4 vb = *(const float4*)(Bbase + (size_t)row * H2_ + k0 + c4);
            *(half4*)&Bh[row * 40 + c4] = cvt4(vb);
        }
        __syncthreads();
        half8 a_f[4], b_f[4];
#pragma unroll
        for (int i = 0; i < 4; i++) {
            a_f[i] = *(const half8*)&Ah[(wm * 64 + i * 16 + ml) * 40 + quad * 8];
            b_f[i] = *(const half8*)&Bh[(wn * 64 + i * 16 + ml) * 40 + quad * 8];
        }
#pragma unroll
        for (int i = 0; i < 4; i++)
#pragma unroll
            for (int j = 0; j < 4; j++)
                acc[i][j] = MFMA16(a_f[i], b_f[j], acc[i][j], 0, 0, 0);
        __syncthreads();
    }
    float* Cbase = out + (size_t)rb * 128 * H_ + (size_t)hb * 128;
#pragma unroll
    for (int j = 0; j < 4; j++) {
        const int cc = wn * 64 + j * 16 + ml;
        const float bj = bias[hb * 128 + cc];
#pragma unroll
        for (int i = 0; i < 4; i++)
#pragma unroll
            for (int r = 0; r < 4; r++) {
                const int rr = wm * 64 + i * 16 + quad * 4 + r;
                Cbase[(size_t)rr * H_ + cc] = tanhf(acc[i][j][r] + bj);
            }
    }
}

extern "C" void kernel_launch(void* const* d_in, const int* in_sizes, int n_in,
                              void* d_out, int out_size, void* d_ws, size_t ws_size,
                              hipStream_t stream) {
    const float* enc  = (const float*)d_in[0];
    const float* dec  = (const float*)d_in[1];
    const float* W    = (const float*)d_in[2];
    const float* bias = (const float*)d_in[3];

    float* out  = (float*)d_out;                              // [B,T,H]  fp32
    float* attn = (float*)d_out + (size_t)B_ * T_ * H_;       // [B,T,S]  fp32
    h16*   ctx  = (h16*)d_ws;                                 // [B,T,H]  f16 (67 MB)

    qk_kernel<<<dim3(S_ / 128, T_ / 128, B_), 256, 0, stream>>>(dec, enc, attn);
    softmax_kernel<<<dim3(B_ * T_), 256, 0, stream>>>(attn);
    av_kernel<<<dim3(H_ / 128, T_ / 128, B_), 256, 0, stream>>>(attn, enc, ctx);
    out_kernel<<<dim3(H_ / 128, (B_ * T_) / 128), 256, 0, stream>>>(ctx, dec, W, bias, out);
}

// Round 3
// 1607.659 us; speedup vs baseline: 1.6860x; 1.6860x over previous
//
#include <hip/hip_runtime.h>
#include <math.h>
#include <stdint.h>

#define B_   16
#define T_   2048
#define S_   2048
#define H_   1024
#define H2_  2048

typedef _Float16 h16;
typedef h16  half8 __attribute__((ext_vector_type(8)));
typedef h16  half4 __attribute__((ext_vector_type(4)));
typedef float f32x4 __attribute__((ext_vector_type(4)));

#define MFMA16 __builtin_amdgcn_mfma_f32_16x16x32_f16

typedef __attribute__((address_space(3))) uint32_t lds_u32;
typedef const __attribute__((address_space(1))) uint32_t glb_u32;

__device__ __forceinline__ void async16(const void* g, void* l) {
    __builtin_amdgcn_global_load_lds((glb_u32*)g, (lds_u32*)l, 16, 0, 0);
}

// stage a 128-row x 32-half tile (row-major, ld bytes between rows) into LDS
// laid out as 128 rows x 64B, unpadded (m97 layout). 4 waves x 2 chunks x 1KB.
__device__ __forceinline__ void stage_tile(const char* gbase, size_t ld,
                                           h16* lds, int wave, int lane) {
#pragma unroll
    for (int q = 0; q < 2; q++) {
        const int chunk = q * 4 + wave;            // 0..7, 1KB each
        const int row   = chunk * 16 + (lane >> 2);
        const int seg   = lane & 3;
        const void* g = gbase + (size_t)row * ld + seg * 16;
        void* l = (void*)((char*)lds + chunk * 1024);
        async16(g, l);
    }
}

__device__ __forceinline__ half4 cvt4(const float4 v) {
    half4 r;
    r[0] = (h16)v.x; r[1] = (h16)v.y; r[2] = (h16)v.z; r[3] = (h16)v.w;
    return r;
}

// ======================= prep: fp32 -> f16 hi/lo split =======================
__global__ __launch_bounds__(256)
void split_kernel(const float4* __restrict__ src, half4* __restrict__ hi,
                  half4* __restrict__ lo, int n4) {
    for (int i = blockIdx.x * 256 + threadIdx.x; i < n4; i += gridDim.x * 256) {
        const float4 v = src[i];
        half4 h, l;
        h[0] = (h16)v.x; h[1] = (h16)v.y; h[2] = (h16)v.z; h[3] = (h16)v.w;
        l[0] = (h16)(v.x - (float)h[0]);
        l[1] = (h16)(v.y - (float)h[1]);
        l[2] = (h16)(v.z - (float)h[2]);
        l[3] = (h16)(v.w - (float)h[3]);
        hi[i] = h; lo[i] = l;
    }
}

__global__ __launch_bounds__(256)
void cvt_kernel(const float4* __restrict__ src, half4* __restrict__ dst, int n4) {
    for (int i = blockIdx.x * 256 + threadIdx.x; i < n4; i += gridDim.x * 256) {
        dst[i] = cvt4(src[i]);
    }
}

// ============== prep: encT[b][h][s] = (h16)enc[b][s][h] ======================
__global__ __launch_bounds__(256)
void transpose_kernel(const float* __restrict__ enc, h16* __restrict__ encT) {
    __shared__ float tile[64 * 65];
    const int s0 = blockIdx.x * 64, h0 = blockIdx.y * 64, b = blockIdx.z;
    const int tid = threadIdx.x;
#pragma unroll
    for (int i = 0; i < 4; i++) {
        const int t = tid + i * 256;
        const int s = t >> 4, c4 = (t & 15) << 2;
        const float4 v = *(const float4*)(enc + ((size_t)(b * S_ + s0 + s)) * H_ + h0 + c4);
        tile[s * 65 + c4 + 0] = v.x;
        tile[s * 65 + c4 + 1] = v.y;
        tile[s * 65 + c4 + 2] = v.z;
        tile[s * 65 + c4 + 3] = v.w;
    }
    __syncthreads();
#pragma unroll
    for (int q = 0; q < 2; q++) {
        const int task = tid * 2 + q;          // 0..511
        const int h = task >> 3, seg = task & 7;
        half8 o;
#pragma unroll
        for (int k = 0; k < 8; k++) o[k] = (h16)tile[(seg * 8 + k) * 65 + h];
        *(half8*)(encT + ((size_t)(b * H_ + h0 + h)) * S_ + s0 + seg * 8) = o;
    }
}

// ======== K1 fast: logits = dec @ enc^T (hi/lo 3-pass, async staging) ========
__global__ __launch_bounds__(256)
void qk2_kernel(const h16* __restrict__ dhi, const h16* __restrict__ dlo,
                const h16* __restrict__ ehi, const h16* __restrict__ elo,
                float* __restrict__ logits) {
    __shared__ __align__(16) h16 Ah[128*32], Al[128*32], Bh[128*32], Bl[128*32];
    const int tid = threadIdx.x;
    const int sb = blockIdx.x, tb = blockIdx.y, b = blockIdx.z;
    const int wave = tid >> 6, lane = tid & 63;
    const int wm = wave & 1, wn = wave >> 1;
    const int ml = lane & 15, quad = lane >> 4;

    const char* Ahi = (const char*)(dhi + ((size_t)b * T_ + (size_t)tb * 128) * H_);
    const char* Alo = (const char*)(dlo + ((size_t)b * T_ + (size_t)tb * 128) * H_);
    const char* Bhi = (const char*)(ehi + ((size_t)b * S_ + (size_t)sb * 128) * H_);
    const char* Blo = (const char*)(elo + ((size_t)b * S_ + (size_t)sb * 128) * H_);

    f32x4 acc[4][4];
#pragma unroll
    for (int i = 0; i < 4; i++)
#pragma unroll
        for (int j = 0; j < 4; j++) acc[i][j] = (f32x4){0.f, 0.f, 0.f, 0.f};

    for (int k0 = 0; k0 < H_; k0 += 32) {
        stage_tile(Ahi + k0 * 2, H_ * 2, Ah, wave, lane);
        stage_tile(Alo + k0 * 2, H_ * 2, Al, wave, lane);
        stage_tile(Bhi + k0 * 2, H_ * 2, Bh, wave, lane);
        stage_tile(Blo + k0 * 2, H_ * 2, Bl, wave, lane);
        __syncthreads();
        half8 a_h[4], a_l[4], b_h[4], b_l[4];
#pragma unroll
        for (int i = 0; i < 4; i++) {
            a_h[i] = *(const half8*)&Ah[(wm * 64 + i * 16 + ml) * 32 + quad * 8];
            a_l[i] = *(const half8*)&Al[(wm * 64 + i * 16 + ml) * 32 + quad * 8];
            b_h[i] = *(const half8*)&Bh[(wn * 64 + i * 16 + ml) * 32 + quad * 8];
            b_l[i] = *(const half8*)&Bl[(wn * 64 + i * 16 + ml) * 32 + quad * 8];
        }
#pragma unroll
        for (int i = 0; i < 4; i++)
#pragma unroll
            for (int j = 0; j < 4; j++) {
                acc[i][j] = MFMA16(a_h[i], b_h[j], acc[i][j], 0, 0, 0);
                acc[i][j] = MFMA16(a_h[i], b_l[j], acc[i][j], 0, 0, 0);
                acc[i][j] = MFMA16(a_l[i], b_h[j], acc[i][j], 0, 0, 0);
            }
        __syncthreads();
    }
    float* Cbase = logits + ((size_t)b * T_ + (size_t)tb * 128) * S_ + (size_t)sb * 128;
#pragma unroll
    for (int i = 0; i < 4; i++)
#pragma unroll
        for (int j = 0; j < 4; j++)
#pragma unroll
            for (int r = 0; r < 4; r++) {
                const int rr = wm * 64 + i * 16 + quad * 4 + r;
                const int cc = wn * 64 + j * 16 + ml;
                Cbase[(size_t)rr * S_ + cc] = acc[i][j][r];
            }
}

// ===================== K2 fast: softmax + f16 copy ===========================
__global__ __launch_bounds__(256)
void softmax2_kernel(float* __restrict__ attn, h16* __restrict__ attnh) {
    float* p  = attn  + (size_t)blockIdx.x * S_;
    h16*   ph = attnh + (size_t)blockIdx.x * S_;
    const int tid = threadIdx.x;
    float v[8];
    float m = -1e30f;
#pragma unroll
    for (int i = 0; i < 8; i++) { v[i] = p[tid + i * 256]; m = fmaxf(m, v[i]); }
#pragma unroll
    for (int off = 32; off > 0; off >>= 1) m = fmaxf(m, __shfl_xor(m, off));
    __shared__ float sm[4];
    __shared__ float ss[4];
    if ((tid & 63) == 0) sm[tid >> 6] = m;
    __syncthreads();
    m = fmaxf(fmaxf(sm[0], sm[1]), fmaxf(sm[2], sm[3]));
    float s = 0.f;
#pragma unroll
    for (int i = 0; i < 8; i++) { v[i] = __expf(v[i] - m); s += v[i]; }
#pragma unroll
    for (int off = 32; off > 0; off >>= 1) s += __shfl_xor(s, off);
    if ((tid & 63) == 0) ss[tid >> 6] = s;
    __syncthreads();
    s = ss[0] + ss[1] + ss[2] + ss[3];
    const float inv = 1.0f / s;
#pragma unroll
    for (int i = 0; i < 8; i++) {
        const float a = v[i] * inv;
        p[tid + i * 256]  = a;
        ph[tid + i * 256] = (h16)a;
    }
}

// ============ K3 fast: ctx = attnh @ encT^T (both f16, async) ================
__global__ __launch_bounds__(256)
void av2_kernel(const h16* __restrict__ attnh, const h16* __restrict__ encT,
                h16* __restrict__ ctx) {
    __shared__ __align__(16) h16 At[128*32], Bt[128*32];
    const int tid = threadIdx.x;
    const int hb = blockIdx.x, tb = blockIdx.y, b = blockIdx.z;
    const int wave = tid >> 6, lane = tid & 63;
    const int wm = wave & 1, wn = wave >> 1;
    const int ml = lane & 15, quad = lane >> 4;

    const char* Abase = (const char*)(attnh + ((size_t)b * T_ + (size_t)tb * 128) * S_);
    const char* Bbase = (const char*)(encT + ((size_t)b * H_ + (size_t)hb * 128) * S_);

    f32x4 acc[4][4];
#pragma unroll
    for (int i = 0; i < 4; i++)
#pragma unroll
        for (int j = 0; j < 4; j++) acc[i][j] = (f32x4){0.f, 0.f, 0.f, 0.f};

    for (int k0 = 0; k0 < S_; k0 += 32) {
        stage_tile(Abase + k0 * 2, S_ * 2, At, wave, lane);
        stage_tile(Bbase + k0 * 2, S_ * 2, Bt, wave, lane);
        __syncthreads();
        half8 a_f[4], b_f[4];
#pragma unroll
        for (int i = 0; i < 4; i++) {
            a_f[i] = *(const half8*)&At[(wm * 64 + i * 16 + ml) * 32 + quad * 8];
            b_f[i] = *(const half8*)&Bt[(wn * 64 + i * 16 + ml) * 32 + quad * 8];
        }
#pragma unroll
        for (int i = 0; i < 4; i++)
#pragma unroll
            for (int j = 0; j < 4; j++)
                acc[i][j] = MFMA16(a_f[i], b_f[j], acc[i][j], 0, 0, 0);
        __syncthreads();
    }
    h16* Cbase = ctx + ((size_t)b * T_ + (size_t)tb * 128) * H_ + (size_t)hb * 128;
#pragma unroll
    for (int i = 0; i < 4; i++)
#pragma unroll
        for (int j = 0; j < 4; j++)
#pragma unroll
            for (int r = 0; r < 4; r++) {
                const int rr = wm * 64 + i * 16 + quad * 4 + r;
                const int cc = wn * 64 + j * 16 + ml;
                Cbase[(size_t)rr * H_ + cc] = (h16)acc[i][j][r];
            }
}

// ====== K4 fast: out = tanh([ctx, dec_hi] @ Wh^T + bias) (f16, async) ========
__global__ __launch_bounds__(256)
void out2_kernel(const h16* __restrict__ ctx, const h16* __restrict__ dech,
                 const h16* __restrict__ Wh, const float* __restrict__ bias,
                 float* __restrict__ out) {
    __shared__ __align__(16) h16 At[128*32], Bt[128*32];
    const int tid = threadIdx.x;
    const int hb = blockIdx.x, rb = blockIdx.y;
    const int wave = tid >> 6, lane = tid & 63;
    const int wm = wave & 1, wn = wave >> 1;
    const int ml = lane & 15, quad = lane >> 4;

    const char* A1 = (const char*)(ctx  + (size_t)rb * 128 * H_);
    const char* A2 = (const char*)(dech + (size_t)rb * 128 * H_);
    const char* Bbase = (const char*)(Wh + (size_t)hb * 128 * H2_);

    f32x4 acc[4][4];
#pragma unroll
    for (int i = 0; i < 4; i++)
#pragma unroll
        for (int j = 0; j < 4; j++) acc[i][j] = (f32x4){0.f, 0.f, 0.f, 0.f};

    for (int k0 = 0; k0 < H2_; k0 += 32) {
        const char* Ab = (k0 < H_) ? (A1 + k0 * 2) : (A2 + (k0 - H_) * 2);
        stage_tile(Ab, H_ * 2, At, wave, lane);
        stage_tile(Bbase + k0 * 2, H2_ * 2, Bt, wave, lane);
        __syncthreads();
        half8 a_f[4], b_f[4];
#pragma unroll
        for (int i = 0; i < 4; i++) {
            a_f[i] = *(const half8*)&At[(wm * 64 + i * 16 + ml) * 32 + quad * 8];
            b_f[i] = *(const half8*)&Bt[(wn * 64 + i * 16 + ml) * 32 + quad * 8];
        }
#pragma unroll
        for (int i = 0; i < 4; i++)
#pragma unroll
            for (int j = 0; j < 4; j++)
                acc[i][j] = MFMA16(a_f[i], b_f[j], acc[i][j], 0, 0, 0);
        __syncthreads();
    }
    float* Cbase = out + (size_t)rb * 128 * H_ + (size_t)hb * 128;
#pragma unroll
    for (int j = 0; j < 4; j++) {
        const int cc = wn * 64 + j * 16 + ml;
        const float bj = bias[hb * 128 + cc];
#pragma unroll
        for (int i = 0; i < 4; i++)
#pragma unroll
            for (int r = 0; r < 4; r++) {
                const int rr = wm * 64 + i * 16 + quad * 4 + r;
                Cbase[(size_t)rr * H_ + cc] = tanhf(acc[i][j][r] + bj);
            }
    }
}

// ====================== fallback (round-2) kernels ===========================
__device__ __forceinline__ void split4(const float4 v, half4& hi, half4& lo) {
    h16 h0 = (h16)v.x, h1 = (h16)v.y, h2 = (h16)v.z, h3 = (h16)v.w;
    hi[0] = h0; hi[1] = h1; hi[2] = h2; hi[3] = h3;
    lo[0] = (h16)(v.x - (float)h0);
    lo[1] = (h16)(v.y - (float)h1);
    lo[2] = (h16)(v.z - (float)h2);
    lo[3] = (h16)(v.w - (float)h3);
}

__global__ __launch_bounds__(256)
void qk_kernel(const float* __restrict__ dec, const float* __restrict__ enc,
               float* __restrict__ logits) {
    __shared__ __align__(16) h16 Ah[128*40], Al[128*40], Bh[128*40], Bl[128*40];
    const int tid  = threadIdx.x;
    const int sb = blockIdx.x, tb = blockIdx.y, b = blockIdx.z;
    const int wave = tid >> 6, lane = tid & 63;
    const int wm = wave & 1, wn = wave >> 1;
    const int ml = lane & 15, quad = lane >> 4;
    const float* Abase = dec + ((size_t)b * T_ + (size_t)tb * 128) * (size_t)H_;
    const float* Bbase = enc + ((size_t)b * S_ + (size_t)sb * 128) * (size_t)H_;
    f32x4 acc[4][4];
#pragma unroll
    for (int i = 0; i < 4; i++)
#pragma unroll
        for (int j = 0; j < 4; j++) acc[i][j] = (f32x4){0.f, 0.f, 0.f, 0.f};
    for (int k0 = 0; k0 < H_; k0 += 32) {
#pragma unroll
        for (int f = tid; f < 1024; f += 256) {
            const int row = f >> 3, c4 = (f & 7) << 2;
            const float4 va = *(const float4*)(Abase + (size_t)row * H_ + k0 + c4);
            const float4 vb = *(const float4*)(Bbase + (size_t)row * H_ + k0 + c4);
            half4 ah, al, bh, bl;
            split4(va, ah, al);
            split4(vb, bh, bl);
            const int base = row * 40 + c4;
            *(half4*)&Ah[base] = ah; *(half4*)&Al[base] = al;
            *(half4*)&Bh[base] = bh; *(half4*)&Bl[base] = bl;
        }
        __syncthreads();
        half8 a_h[4], a_l[4], b_h[4], b_l[4];
#pragma unroll
        for (int i = 0; i < 4; i++) {
            const int ra = (wm * 64 + i * 16 + ml) * 40 + quad * 8;
            a_h[i] = *(const half8*)&Ah[ra];
            a_l[i] = *(const half8*)&Al[ra];
            const int rb = (wn * 64 + i * 16 + ml) * 40 + quad * 8;
            b_h[i] = *(const half8*)&Bh[rb];
            b_l[i] = *(const half8*)&Bl[rb];
        }
#pragma unroll
        for (int i = 0; i < 4; i++)
#pragma unroll
            for (int j = 0; j < 4; j++) {
                acc[i][j] = MFMA16(a_h[i], b_h[j], acc[i][j], 0, 0, 0);
                acc[i][j] = MFMA16(a_h[i], b_l[j], acc[i][j], 0, 0, 0);
                acc[i][j] = MFMA16(a_l[i], b_h[j], acc[i][j], 0, 0, 0);
            }
        __syncthreads();
    }
    float* Cbase = logits + ((size_t)b * T_ + (size_t)tb * 128) * (size_t)S_ + (size_t)sb * 128;
#pragma unroll
    for (int i = 0; i < 4; i++)
#pragma unroll
        for (int j = 0; j < 4; j++)
#pragma unroll
            for (int r = 0; r < 4; r++) {
                const int rr = wm * 64 + i * 16 + quad * 4 + r;
                const int cc = wn * 64 + j * 16 + ml;
                Cbase[(size_t)rr * S_ + cc] = acc[i][j][r];
            }
}

__global__ __launch_bounds__(256)
void softmax_kernel(float* __restrict__ attn) {
    float* p = attn + (size_t)blockIdx.x * S_;
    const int tid = threadIdx.x;
    float v[8];
    float m = -1e30f;
#pragma unroll
    for (int i = 0; i < 8; i++) { v[i] = p[tid + i * 256]; m = fmaxf(m, v[i]); }
#pragma unroll
    for (int off = 32; off > 0; off >>= 1) m = fmaxf(m, __shfl_xor(m, off));
    __shared__ float sm[4];
    __shared__ float ss[4];
    if ((tid & 63) == 0) sm[tid >> 6] = m;
    __syncthreads();
    m = fmaxf(fmaxf(sm[0], sm[1]), fmaxf(sm[2], sm[3]));
    float s = 0.f;
#pragma unroll
    for (int i = 0; i < 8; i++) { v[i] = __expf(v[i] - m); s += v[i]; }
#pragma unroll
    for (int off = 32; off > 0; off >>= 1) s += __shfl_xor(s, off);
    if ((tid & 63) == 0) ss[tid >> 6] = s;
    __syncthreads();
    s = ss[0] + ss[1] + ss[2] + ss[3];
    const float inv = 1.0f / s;
#pragma unroll
    for (int i = 0; i < 8; i++) p[tid + i * 256] = v[i] * inv;
}

__global__ __launch_bounds__(256)
void av_kernel(const float* __restrict__ attn, const float* __restrict__ enc,
               h16* __restrict__ ctx) {
    __shared__ __align__(16) h16 Ah[128*40], Bt[128*40];
    const int tid = threadIdx.x;
    const int hb = blockIdx.x, tb = blockIdx.y, b = blockIdx.z;
    const int wave = tid >> 6, lane = tid & 63;
    const int wm = wave & 1, wn = wave >> 1;
    const int ml = lane & 15, quad = lane >> 4;
    const float* Abase = attn + ((size_t)b * T_ + (size_t)tb * 128) * (size_t)S_;
    const float* Bbase = enc + (size_t)b * S_ * H_ + (size_t)hb * 128;
    f32x4 acc[4][4];
#pragma unroll
    for (int i = 0; i < 4; i++)
#pragma unroll
        for (int j = 0; j < 4; j++) acc[i][j] = (f32x4){0.f, 0.f, 0.f, 0.f};
    for (int k0 = 0; k0 < S_; k0 += 32) {
#pragma unroll
        for (int f = tid; f < 1024; f += 256) {
            const int row = f >> 3, c4 = (f & 7) << 2;
            const float4 va = *(const float4*)(Abase + (size_t)row * S_ + k0 + c4);
            *(half4*)&Ah[row * 40 + c4] = cvt4(va);
        }
#pragma unroll
        for (int f = tid; f < 1024; f += 256) {
            const int kr = f >> 5, c4 = (f & 31) << 2;
            const float4 vb = *(const float4*)(Bbase + (size_t)(k0 + kr) * H_ + c4);
            Bt[(c4 + 0) * 40 + kr] = (h16)vb.x;
            Bt[(c4 + 1) * 40 + kr] = (h16)vb.y;
            Bt[(c4 + 2) * 40 + kr] = (h16)vb.z;
            Bt[(c4 + 3) * 40 + kr] = (h16)vb.w;
        }
        __syncthreads();
        half8 a_f[4], b_f[4];
#pragma unroll
        for (int i = 0; i < 4; i++) {
            a_f[i] = *(const half8*)&Ah[(wm * 64 + i * 16 + ml) * 40 + quad * 8];
            b_f[i] = *(const half8*)&Bt[(wn * 64 + i * 16 + ml) * 40 + quad * 8];
        }
#pragma unroll
        for (int i = 0; i < 4; i++)
#pragma unroll
            for (int j = 0; j < 4; j++)
                acc[i][j] = MFMA16(a_f[i], b_f[j], acc[i][j], 0, 0, 0);
        __syncthreads();
    }
    h16* Cbase = ctx + ((size_t)b * T_ + (size_t)tb * 128) * (size_t)H_ + (size_t)hb * 128;
#pragma unroll
    for (int i = 0; i < 4; i++)
#pragma unroll
        for (int j = 0; j < 4; j++)
#pragma unroll
            for (int r = 0; r < 4; r++) {
                const int rr = wm * 64 + i * 16 + quad * 4 + r;
                const int cc = wn * 64 + j * 16 + ml;
                Cbase[(size_t)rr * H_ + cc] = (h16)acc[i][j][r];
            }
}

__global__ __launch_bounds__(256)
void out_kernel(const h16* __restrict__ ctx, const float* __restrict__ dec,
                const float* __restrict__ W, const float* __restrict__ bias,
                float* __restrict__ out) {
    __shared__ __align__(16) h16 Ah[128*40], Bh[128*40];
    const int tid = threadIdx.x;
    const int hb = blockIdx.x, rb = blockIdx.y;
    const int wave = tid >> 6, lane = tid & 63;
    const int wm = wave & 1, wn = wave >> 1;
    const int ml = lane & 15, quad = lane >> 4;
    const h16*  A1 = ctx + (size_t)rb * 128 * H_;
    const float* A2 = dec + (size_t)rb * 128 * H_;
    const float* Bbase = W + (size_t)hb * 128 * H2_;
    f32x4 acc[4][4];
#pragma unroll
    for (int i = 0; i < 4; i++)
#pragma unroll
        for (int j = 0; j < 4; j++) acc[i][j] = (f32x4){0.f, 0.f, 0.f, 0.f};
    for (int k0 = 0; k0 < H2_; k0 += 32) {
        if (k0 < H_) {
#pragma unroll
            for (int f = tid; f < 512; f += 256) {
                const int row = f >> 2, c8 = (f & 3) << 3;
                const half8 v = *(const half8*)(A1 + (size_t)row * H_ + k0 + c8);
                *(half8*)&Ah[row * 40 + c8] = v;
            }
        } else {
#pragma unroll
            for (int f = tid; f < 1024; f += 256) {
                const int row = f >> 3, c4 = (f & 7) << 2;
                const float4 va = *(const float4*)(A2 + (size_t)row * H_ + (k0 - H_) + c4);
                *(half4*)&Ah[row * 40 + c4] = cvt4(va);
            }
        }
#pragma unroll
        for (int f = tid; f < 1024; f += 256) {
            const int row = f >> 3, c4 = (f & 7) << 2;
            const float4 vb = *(const float4*)(Bbase + (size_t)row * H2_ + k0 + c4);
            *(half4*)&Bh[row * 40 + c4] = cvt4(vb);
        }
        __syncthreads();
        half8 a_f[4], b_f[4];
#pragma unroll
        for (int i = 0; i < 4; i++) {
            a_f[i] = *(const half8*)&Ah[(wm * 64 + i * 16 + ml) * 40 + quad * 8];
            b_f[i] = *(const half8*)&Bh[(wn * 64 + i * 16 + ml) * 40 + quad * 8];
        }
#pragma unroll
        for (int i = 0; i < 4; i++)
#pragma unroll
            for (int j = 0; j < 4; j++)
                acc[i][j] = MFMA16(a_f[i], b_f[j], acc[i][j], 0, 0, 0);
        __syncthreads();
    }
    float* Cbase = out + (size_t)rb * 128 * H_ + (size_t)hb * 128;
#pragma unroll
    for (int j = 0; j < 4; j++) {
        const int cc = wn * 64 + j * 16 + ml;
        const float bj = bias[hb * 128 + cc];
#pragma unroll
        for (int i = 0; i < 4; i++)
#pragma unroll
            for (int r = 0; r < 4; r++) {
                const int rr = wm * 64 + i * 16 + quad * 4 + r;
                Cbase[(size_t)rr * H_ + cc] = tanhf(acc[i][j][r] + bj);
            }
    }
}

// ============================== launch =======================================
extern "C" void kernel_launch(void* const* d_in, const int* in_sizes, int n_in,
                              void* d_out, int out_size, void* d_ws, size_t ws_size,
                              hipStream_t stream) {
    const float* enc  = (const float*)d_in[0];
    const float* dec  = (const float*)d_in[1];
    const float* W    = (const float*)d_in[2];
    const float* bias = (const float*)d_in[3];

    float* out  = (float*)d_out;                              // [B,T,H]  fp32
    float* attn = (float*)d_out + (size_t)B_ * T_ * H_;       // [B,T,S]  fp32

    const size_t NN = (size_t)B_ * T_ * H_;                   // 33,554,432
    const size_t NEED = NN * 10 + (size_t)H_ * H2_ * 2;       // ~340 MB

    if (ws_size >= NEED) {
        char* ws = (char*)d_ws;
        h16* dec_hi = (h16*)(ws);                 // NN halves
        h16* enc_hi = (h16*)(ws + NN * 2);        // NN halves (reused as ctx)
        h16* dec_lo = (h16*)(ws + NN * 4);        // NN halves
        h16* enc_lo = (h16*)(ws + NN * 6);        // NN halves
        h16* attnh  = (h16*)(ws + NN * 4);        // 2*NN halves, aliases dec_lo+enc_lo
        h16* ctx    = enc_hi;                     // aliases enc_hi (dead after qk2)
        h16* encT   = (h16*)(ws + NN * 8);        // NN halves
        h16* Wh     = (h16*)(ws + NN * 10);       // H*2H halves

        const int n4 = (int)(NN / 4);
        split_kernel<<<dim3(8192), 256, 0, stream>>>((const float4*)dec, (half4*)dec_hi, (half4*)dec_lo, n4);
        split_kernel<<<dim3(8192), 256, 0, stream>>>((const float4*)enc, (half4*)enc_hi, (half4*)enc_lo, n4);
        cvt_kernel<<<dim3(2048), 256, 0, stream>>>((const float4*)W, (half4*)Wh, H_ * H2_ / 4);
        transpose_kernel<<<dim3(S_ / 64, H_ / 64, B_), 256, 0, stream>>>(enc, encT);

        qk2_kernel<<<dim3(S_ / 128, T_ / 128, B_), 256, 0, stream>>>(dec_hi, dec_lo, enc_hi, enc_lo, attn);
        softmax2_kernel<<<dim3(B_ * T_), 256, 0, stream>>>(attn, attnh);
        av2_kernel<<<dim3(H_ / 128, T_ / 128, B_), 256, 0, stream>>>(attnh, encT, ctx);
        out2_kernel<<<dim3(H_ / 128, (B_ * T_) / 128), 256, 0, stream>>>(ctx, dec_hi, Wh, bias, out);
    } else {
        h16* ctx = (h16*)d_ws;  // 67 MB
        qk_kernel<<<dim3(S_ / 128, T_ / 128, B_), 256, 0, stream>>>(dec, enc, attn);
        softmax_kernel<<<dim3(B_ * T_), 256, 0, stream>>>(attn);
        av_kernel<<<dim3(H_ / 128, T_ / 128, B_), 256, 0, stream>>>(attn, enc, ctx);
        out_kernel<<<dim3(H_ / 128, (B_ * T_) / 128), 256, 0, stream>>>(ctx, dec, W, bias, out);
    }
}